// Round 2
// baseline (293.291 us; speedup 1.0000x reference)
//
#include <hip/hip_runtime.h>

// B=16, Q=512, P=2048, D=256, H=8, DH=32
#define BB 16
#define QQ 512
#define PP 2048
#define DD 256
#define HH 8
#define DH 32

typedef __attribute__((ext_vector_type(8))) short short8;
typedef __attribute__((ext_vector_type(4))) float f32x4;

static __device__ __forceinline__ unsigned short f2bf(float f) {
  union { float f; unsigned u; } v; v.f = f;
  unsigned u = v.u;
  unsigned r = (u + 0x7FFFu + ((u >> 16) & 1u)) >> 16;  // RNE
  return (unsigned short)r;
}

static __device__ __forceinline__ short8 load_f32x8_bf16(const float* p) {
  const float4* p4 = (const float4*)p;
  float4 a = p4[0], b = p4[1];
  short8 r;
  r[0] = (short)f2bf(a.x); r[1] = (short)f2bf(a.y);
  r[2] = (short)f2bf(a.z); r[3] = (short)f2bf(a.w);
  r[4] = (short)f2bf(b.x); r[5] = (short)f2bf(b.y);
  r[6] = (short)f2bf(b.z); r[7] = (short)f2bf(b.w);
  return r;
}

// ---------------- Kernel 1: input projections ----------------
// C[m,n] = sum_k in[m,k]*w[n,k] + bias[n], written as bf16 into attention layouts.
// mode 0: queries -> Qb [B,H,Q,32]            (M=8192,  N=256, rows/batch=512)
// mode 1: sources -> Kb [B,H,P,32] (n<256), Vt [B,H,32,P] (n>=256)  (M=32768, N=512)
__global__ __launch_bounds__(256) void proj_kernel(
    const float* __restrict__ in, const float* __restrict__ w,
    const float* __restrict__ bias,
    unsigned short* __restrict__ out0, unsigned short* __restrict__ out1,
    int mode) {
  int nt = blockIdx.x, mt = blockIdx.y;  // x = N-tiles (fast) for A-row L2 reuse
  int tid = threadIdx.x;
  int wid = tid >> 6, lane = tid & 63;
  int wm = wid >> 1, wn = wid & 1;
  int m0 = mt * 64 + wm * 32;
  int n0 = nt * 64 + wn * 32;
  int lr = lane & 15, lk = lane >> 4;

  f32x4 acc[2][2] = {};
  for (int k0 = 0; k0 < 256; k0 += 32) {
    short8 af[2], bfr[2];
    for (int i = 0; i < 2; i++)
      af[i] = load_f32x8_bf16(in + (size_t)(m0 + i * 16 + lr) * 256 + k0 + lk * 8);
    for (int j = 0; j < 2; j++)
      bfr[j] = load_f32x8_bf16(w + (size_t)(n0 + j * 16 + lr) * 256 + k0 + lk * 8);
    for (int i = 0; i < 2; i++)
      for (int j = 0; j < 2; j++)
        acc[i][j] = __builtin_amdgcn_mfma_f32_16x16x32_bf16(af[i], bfr[j], acc[i][j], 0, 0, 0);
  }
  for (int i = 0; i < 2; i++)
    for (int j = 0; j < 2; j++) {
      int n = n0 + j * 16 + lr;  // D col = lane&15
      float bv = bias[n];
      for (int r = 0; r < 4; r++) {
        int m = m0 + i * 16 + lk * 4 + r;  // D row = 4*(lane>>4)+r
        unsigned short o = f2bf(acc[i][j][r] + bv);
        if (mode == 0) {
          int b = m >> 9, q = m & 511;
          out0[(((size_t)(b * 8 + (n >> 5)) * 512 + q) * 32) + (n & 31)] = o;
        } else {
          int b = m >> 11, p = m & 2047;
          if (n < 256) {
            out0[(((size_t)(b * 8 + (n >> 5)) * 2048 + p) * 32) + (n & 31)] = o;
          } else {
            int n2 = n - 256;
            out1[((size_t)(b * 8 + (n2 >> 5)) * 32 + (n2 & 31)) * 2048 + p] = o;
          }
        }
      }
    }
}

// ---------------- Kernel 2: masked flash attention ----------------
// grid.x = B*H (128), grid.y = Q/64 (8). 4 waves, wave = 16 q-rows.
// attn_mask is int32 (one int per (b,q,p)), nonzero = masked-out.
__global__ __launch_bounds__(256) void attn_kernel(
    const unsigned short* __restrict__ Qb, const unsigned short* __restrict__ Kb,
    const unsigned short* __restrict__ Vt, const int* __restrict__ mask,
    unsigned short* __restrict__ Ob) {
  __shared__ unsigned short Plds[4][16][72];  // per-wave P tile, padded stride
  int bh = blockIdx.x;
  int b = bh >> 3, h = bh & 7;
  int tid = threadIdx.x, wid = tid >> 6, lane = tid & 63;
  int lr = lane & 15, lk = lane >> 4;
  int qbase = blockIdx.y * 64 + wid * 16;
  const float scale = 0.17677669529663687f;  // 1/sqrt(32)

  // Q A-fragment, held for whole kernel
  short8 qa = *(const short8*)(Qb + ((size_t)bh * QQ + qbase + lr) * 32 + lk * 8);

  float mrun[4], lrun[4];
  f32x4 acc[2] = {};
  for (int r = 0; r < 4; r++) { mrun[r] = -1e30f; lrun[r] = 0.f; }

  const unsigned short* Kbase = Kb + (size_t)bh * PP * 32;
  const unsigned short* Vbase = Vt + (size_t)bh * 32 * PP;
  const int* mbase = mask + ((size_t)b * QQ + qbase) * PP;

  for (int p0 = 0; p0 < PP; p0 += 64) {
    // S = Q*K^T for 16 q x 64 keys (4 MFMAs)
    f32x4 s[4];
    for (int f = 0; f < 4; f++) {
      short8 kb = *(const short8*)(Kbase + (size_t)(p0 + f * 16 + lr) * 32 + lk * 8);
      f32x4 z = {};
      s[f] = __builtin_amdgcn_mfma_f32_16x16x32_bf16(qa, kb, z, 0, 0, 0);
    }
    // mask + scale; chunk row-max
    float sv[4][4];
    float cm[4] = {-1e30f, -1e30f, -1e30f, -1e30f};
    for (int f = 0; f < 4; f++)
      for (int r = 0; r < 4; r++) {
        int q = lk * 4 + r;
        int mk = mbase[(size_t)q * PP + p0 + f * 16 + lr];
        float v = mk ? -1e30f : s[f][r] * scale;
        sv[f][r] = v;
        cm[r] = fmaxf(cm[r], v);
      }
    for (int r = 0; r < 4; r++)
      for (int d = 1; d < 16; d <<= 1)
        cm[r] = fmaxf(cm[r], __shfl_xor(cm[r], d, 64));
    float mnew[4], alpha[4], psum[4] = {0.f, 0.f, 0.f, 0.f};
    for (int r = 0; r < 4; r++) {
      mnew[r] = fmaxf(mrun[r], cm[r]);
      alpha[r] = __expf(mrun[r] - mnew[r]);
      mrun[r] = mnew[r];
    }
    // p = exp(s - mnew) (0 for masked via -1e30), write bf16 to LDS
    for (int f = 0; f < 4; f++)
      for (int r = 0; r < 4; r++) {
        float p = __expf(sv[f][r] - mnew[r]);
        psum[r] += p;
        Plds[wid][lk * 4 + r][f * 16 + lr] = f2bf(p);
      }
    for (int r = 0; r < 4; r++) {
      for (int d = 1; d < 16; d <<= 1) psum[r] += __shfl_xor(psum[r], d, 64);
      lrun[r] = lrun[r] * alpha[r] + psum[r];
    }
    for (int dhf = 0; dhf < 2; dhf++)
      for (int r = 0; r < 4; r++) acc[dhf][r] *= alpha[r];
    __syncthreads();  // make P visible (cross-lane within wave)
    // PV: acc += P[16x64] * V[64x32]
    for (int kc = 0; kc < 2; kc++) {
      short8 pa = *(const short8*)&Plds[wid][lr][kc * 32 + lk * 8];
      for (int dhf = 0; dhf < 2; dhf++) {
        short8 vb = *(const short8*)(Vbase + (size_t)(dhf * 16 + lr) * PP + p0 + kc * 32 + lk * 8);
        acc[dhf] = __builtin_amdgcn_mfma_f32_16x16x32_bf16(pa, vb, acc[dhf], 0, 0, 0);
      }
    }
  }
  // normalize + write O bf16 [B,Q,256]
  for (int dhf = 0; dhf < 2; dhf++)
    for (int r = 0; r < 4; r++) {
      int q = qbase + lk * 4 + r;
      float o = acc[dhf][r] / lrun[r];
      Ob[((size_t)b * QQ + q) * 256 + h * 32 + dhf * 16 + lr] = f2bf(o);
    }
}

// ---------------- Kernel 3: out-proj + bias + residual + LayerNorm ----------------
// 16 rows per block; wave wid owns cols wid*64..+63.
__global__ __launch_bounds__(256) void outln_kernel(
    const unsigned short* __restrict__ Ob, const float* __restrict__ out_w,
    const float* __restrict__ out_b, const float* __restrict__ queries,
    const float* __restrict__ ln_g, const float* __restrict__ ln_b,
    float* __restrict__ out) {
  __shared__ float rowbuf[16][260];
  int mt = blockIdx.x;
  int tid = threadIdx.x, wid = tid >> 6, lane = tid & 63;
  int lr = lane & 15, lk = lane >> 4;
  int m0 = mt * 16;
  f32x4 acc[4] = {};
  for (int k0 = 0; k0 < 256; k0 += 32) {
    short8 af = *(const short8*)(Ob + (size_t)(m0 + lr) * 256 + k0 + lk * 8);
    for (int j = 0; j < 4; j++) {
      short8 bfr = load_f32x8_bf16(out_w + (size_t)(wid * 64 + j * 16 + lr) * 256 + k0 + lk * 8);
      acc[j] = __builtin_amdgcn_mfma_f32_16x16x32_bf16(af, bfr, acc[j], 0, 0, 0);
    }
  }
  for (int j = 0; j < 4; j++) {
    int n = wid * 64 + j * 16 + lr;
    float bv = out_b[n];
    for (int r = 0; r < 4; r++) {
      int m = m0 + lk * 4 + r;
      rowbuf[lk * 4 + r][n] = acc[j][r] + bv + queries[(size_t)m * 256 + n];
    }
  }
  __syncthreads();
  int row = tid >> 4, seg = tid & 15;
  float s1 = 0.f, s2 = 0.f, vals[16];
  for (int c = 0; c < 16; c++) {
    float v = rowbuf[row][seg * 16 + c];
    vals[c] = v; s1 += v; s2 += v * v;
  }
  for (int d = 1; d < 16; d <<= 1) {
    s1 += __shfl_xor(s1, d, 64);
    s2 += __shfl_xor(s2, d, 64);
  }
  float mean = s1 * (1.f / 256.f);
  float var = s2 * (1.f / 256.f) - mean * mean;
  float rstd = rsqrtf(var + 1e-5f);
  int m = m0 + row;
  for (int c = 0; c < 16; c++) {
    int col = seg * 16 + c;
    out[(size_t)m * 256 + col] = (vals[c] - mean) * rstd * ln_g[col] + ln_b[col];
  }
}

extern "C" void kernel_launch(void* const* d_in, const int* in_sizes, int n_in,
                              void* d_out, int out_size, void* d_ws, size_t ws_size,
                              hipStream_t stream) {
  const float* sources  = (const float*)d_in[0];
  const float* queries  = (const float*)d_in[1];
  const int* attn_mask  = (const int*)d_in[2];
  const float* in_proj_w = (const float*)d_in[3];
  const float* in_proj_b = (const float*)d_in[4];
  const float* out_w = (const float*)d_in[5];
  const float* out_b = (const float*)d_in[6];
  const float* ln_g  = (const float*)d_in[7];
  const float* ln_b  = (const float*)d_in[8];
  float* out = (float*)d_out;

  unsigned short* Qb = (unsigned short*)d_ws;           // [B,H,Q,32]  2,097,152
  unsigned short* Kb = Qb + (size_t)2097152;            // [B,H,P,32]  8,388,608
  unsigned short* Vt = Kb + (size_t)8388608;            // [B,H,32,P]  8,388,608
  unsigned short* Ob = Vt + (size_t)8388608;            // [B,Q,256]   2,097,152

  dim3 blk(256);
  proj_kernel<<<dim3(4, 128), blk, 0, stream>>>(queries, in_proj_w, in_proj_b, Qb, nullptr, 0);
  proj_kernel<<<dim3(8, 512), blk, 0, stream>>>(sources, in_proj_w + 256 * 256,
                                                in_proj_b + 256, Kb, Vt, 1);
  attn_kernel<<<dim3(128, 8), blk, 0, stream>>>(Qb, Kb, Vt, attn_mask, Ob);
  outln_kernel<<<dim3(512), blk, 0, stream>>>(Ob, out_w, out_b, queries, ln_g, ln_b, out);
}

// Round 3
// 235.203 us; speedup vs baseline: 1.2470x; 1.2470x over previous
//
#include <hip/hip_runtime.h>

// B=16, Q=512, P=2048, D=256, H=8, DH=32
#define BB 16
#define QQ 512
#define PP 2048
#define DD 256
#define HH 8
#define DH 32

typedef __attribute__((ext_vector_type(8))) short short8;
typedef __attribute__((ext_vector_type(4))) float f32x4;

static __device__ __forceinline__ unsigned short f2bf(float f) {
  union { float f; unsigned u; } v; v.f = f;
  unsigned u = v.u;
  unsigned r = (u + 0x7FFFu + ((u >> 16) & 1u)) >> 16;  // RNE
  return (unsigned short)r;
}

static __device__ __forceinline__ short8 load_f32x8_bf16(const float* p) {
  const float4* p4 = (const float4*)p;
  float4 a = p4[0], b = p4[1];
  short8 r;
  r[0] = (short)f2bf(a.x); r[1] = (short)f2bf(a.y);
  r[2] = (short)f2bf(a.z); r[3] = (short)f2bf(a.w);
  r[4] = (short)f2bf(b.x); r[5] = (short)f2bf(b.y);
  r[6] = (short)f2bf(b.z); r[7] = (short)f2bf(b.w);
  return r;
}

// ---------------- Kernel 0a: pack in_proj_w (768x256 f32) -> bf16 ----------------
__global__ __launch_bounds__(256) void pack_w_kernel(const float* __restrict__ w,
                                                     unsigned short* __restrict__ wb) {
  int t = blockIdx.x * 256 + threadIdx.x;  // 24576 threads, 8 elems each
  int i0 = t * 8;
  if (i0 < 768 * 256) {
    short8 v = load_f32x8_bf16(w + i0);
    *(short8*)(wb + i0) = v;
  }
}

// ---------------- Kernel 0b: pack mask (int32) -> 1 bit/key ----------------
// mask64[(b*Q+q)*32 + p/64], bit (p&63) set = masked-out.
__global__ __launch_bounds__(256) void pack_mask_kernel(const int* __restrict__ mask,
                                                        unsigned long long* __restrict__ mask64) {
  int wave = (blockIdx.x * 256 + threadIdx.x) >> 6;  // 8192 waves
  int lane = threadIdx.x & 63;
  const int NG = BB * QQ * (PP / 64);  // 262144 groups
  for (int g = wave; g < NG; g += 8192) {
    int v = mask[(size_t)g * 64 + lane];
    unsigned long long bits = __ballot(v != 0);
    if (lane == 0) mask64[g] = bits;
  }
}

// ---------------- Kernel 1: input projections ----------------
// 8 waves (512 thr): wave-grid 2 (rows) x 4 (cols); wave tile 32 x (NF*16).
// mode 0: queries -> Qb [B,H,Q,32]                       (M=8192,  N=256, NF=4)
// mode 1: sources -> Kb [B,H,P,32] / Vt [B,H,32,P]       (M=32768, N=512, NF=8)
template <int NF>
__global__ __launch_bounds__(512) void proj_kernel(
    const float* __restrict__ in, const unsigned short* __restrict__ wb,
    const float* __restrict__ bias,
    unsigned short* __restrict__ out0, unsigned short* __restrict__ out1,
    int mode) {
  int tid = threadIdx.x;
  int wid = tid >> 6, lane = tid & 63;
  int wm = wid >> 2, wn = wid & 3;
  int lr = lane & 15, lk = lane >> 4;
  int m0 = blockIdx.x * 64 + wm * 32;
  int n0 = wn * NF * 16;

  f32x4 acc[2][NF] = {};
  for (int k0 = 0; k0 < 256; k0 += 32) {
    short8 af[2];
    af[0] = load_f32x8_bf16(in + (size_t)(m0 + lr) * 256 + k0 + lk * 8);
    af[1] = load_f32x8_bf16(in + (size_t)(m0 + 16 + lr) * 256 + k0 + lk * 8);
#pragma unroll
    for (int j = 0; j < NF; j++) {
      short8 bfr = *(const short8*)(wb + (size_t)(n0 + j * 16 + lr) * 256 + k0 + lk * 8);
      acc[0][j] = __builtin_amdgcn_mfma_f32_16x16x32_bf16(af[0], bfr, acc[0][j], 0, 0, 0);
      acc[1][j] = __builtin_amdgcn_mfma_f32_16x16x32_bf16(af[1], bfr, acc[1][j], 0, 0, 0);
    }
  }
#pragma unroll
  for (int i = 0; i < 2; i++)
#pragma unroll
    for (int j = 0; j < NF; j++) {
      int n = n0 + j * 16 + lr;  // D col = lane&15
      float bv = bias[n];
#pragma unroll
      for (int r = 0; r < 4; r++) {
        int m = m0 + i * 16 + lk * 4 + r;  // D row = 4*(lane>>4)+r
        unsigned short o = f2bf(acc[i][j][r] + bv);
        if (mode == 0) {
          int b = m >> 9, q = m & 511;
          out0[(((size_t)(b * 8 + (n >> 5)) * 512 + q) * 32) + (n & 31)] = o;
        } else {
          int b = m >> 11, p = m & 2047;
          if (n < 256) {
            out0[(((size_t)(b * 8 + (n >> 5)) * 2048 + p) * 32) + (n & 31)] = o;
          } else {
            int n2 = n - 256;
            out1[((size_t)(b * 8 + (n2 >> 5)) * 32 + (n2 & 31)) * 2048 + p] = o;
          }
        }
      }
    }
}

// ---------------- Kernel 2: masked flash attention ----------------
// grid.x = Q/64 (8), grid.y = B*H (128)  -> consecutive blocks share K/V in L2.
// 4 waves, wave = 16 q-rows. Bit-packed mask.
__global__ __launch_bounds__(256) void attn_kernel(
    const unsigned short* __restrict__ Qb, const unsigned short* __restrict__ Kb,
    const unsigned short* __restrict__ Vt, const unsigned long long* __restrict__ mask64,
    unsigned short* __restrict__ Ob) {
  __shared__ unsigned short Plds[4][16][72];  // per-wave P tile (wave-private)
  int bh = blockIdx.y;
  int b = bh >> 3, h = bh & 7;
  int tid = threadIdx.x, wid = tid >> 6, lane = tid & 63;
  int lr = lane & 15, lk = lane >> 4;
  int qbase = blockIdx.x * 64 + wid * 16;
  const float scale = 0.17677669529663687f;  // 1/sqrt(32)

  short8 qa = *(const short8*)(Qb + ((size_t)bh * QQ + qbase + lr) * 32 + lk * 8);

  float mrun[4], lrun[4];
  f32x4 acc[2] = {};
  for (int r = 0; r < 4; r++) { mrun[r] = -1e30f; lrun[r] = 0.f; }

  const unsigned short* Kbase = Kb + (size_t)bh * PP * 32;
  const unsigned short* Vbase = Vt + (size_t)bh * 32 * PP;
  const unsigned long long* mbase = mask64 + ((size_t)b * QQ + qbase) * (PP / 64);

  for (int p0 = 0; p0 < PP; p0 += 64) {
    // S = Q*K^T for 16 q x 64 keys (4 MFMAs)
    f32x4 s[4];
#pragma unroll
    for (int f = 0; f < 4; f++) {
      short8 kb = *(const short8*)(Kbase + (size_t)(p0 + f * 16 + lr) * 32 + lk * 8);
      f32x4 z = {};
      s[f] = __builtin_amdgcn_mfma_f32_16x16x32_bf16(qa, kb, z, 0, 0, 0);
    }
    // bit-mask + scale; chunk row-max
    unsigned long long m64[4];
#pragma unroll
    for (int r = 0; r < 4; r++)
      m64[r] = mbase[(size_t)(lk * 4 + r) * (PP / 64) + (p0 >> 6)];
    float sv[4][4];
    float cm[4] = {-1e30f, -1e30f, -1e30f, -1e30f};
#pragma unroll
    for (int f = 0; f < 4; f++)
#pragma unroll
      for (int r = 0; r < 4; r++) {
        int masked = (int)((m64[r] >> (f * 16 + lr)) & 1ull);
        float v = masked ? -1e30f : s[f][r] * scale;
        sv[f][r] = v;
        cm[r] = fmaxf(cm[r], v);
      }
#pragma unroll
    for (int r = 0; r < 4; r++)
#pragma unroll
      for (int d = 1; d < 16; d <<= 1)
        cm[r] = fmaxf(cm[r], __shfl_xor(cm[r], d, 64));
    float mnew[4], alpha[4], psum[4] = {0.f, 0.f, 0.f, 0.f};
#pragma unroll
    for (int r = 0; r < 4; r++) {
      mnew[r] = fmaxf(mrun[r], cm[r]);
      alpha[r] = __expf(mrun[r] - mnew[r]);
      mrun[r] = mnew[r];
    }
#pragma unroll
    for (int f = 0; f < 4; f++)
#pragma unroll
      for (int r = 0; r < 4; r++) {
        float p = __expf(sv[f][r] - mnew[r]);
        psum[r] += p;
        Plds[wid][lk * 4 + r][f * 16 + lr] = f2bf(p);
      }
#pragma unroll
    for (int r = 0; r < 4; r++) {
#pragma unroll
      for (int d = 1; d < 16; d <<= 1) psum[r] += __shfl_xor(psum[r], d, 64);
      lrun[r] = lrun[r] * alpha[r] + psum[r];
    }
#pragma unroll
    for (int dhf = 0; dhf < 2; dhf++)
#pragma unroll
      for (int r = 0; r < 4; r++) acc[dhf][r] *= alpha[r];
    // PV: acc += P[16x64] * V[64x32]. Plds is wave-private: in-wave lgkmcnt
    // ordering (compiler-inserted) suffices, no __syncthreads needed.
#pragma unroll
    for (int kc = 0; kc < 2; kc++) {
      short8 pa = *(const short8*)&Plds[wid][lr][kc * 32 + lk * 8];
#pragma unroll
      for (int dhf = 0; dhf < 2; dhf++) {
        short8 vb = *(const short8*)(Vbase + (size_t)(dhf * 16 + lr) * PP + p0 + kc * 32 + lk * 8);
        acc[dhf] = __builtin_amdgcn_mfma_f32_16x16x32_bf16(pa, vb, acc[dhf], 0, 0, 0);
      }
    }
  }
  // normalize + write O bf16 [B,Q,256]
#pragma unroll
  for (int dhf = 0; dhf < 2; dhf++)
#pragma unroll
    for (int r = 0; r < 4; r++) {
      int q = qbase + lk * 4 + r;
      float o = acc[dhf][r] / lrun[r];
      Ob[((size_t)b * QQ + q) * 256 + h * 32 + dhf * 16 + lr] = f2bf(o);
    }
}

// ---------------- Kernel 3: out-proj + bias + residual + LayerNorm ----------------
__global__ __launch_bounds__(256) void outln_kernel(
    const unsigned short* __restrict__ Ob, const float* __restrict__ out_w,
    const float* __restrict__ out_b, const float* __restrict__ queries,
    const float* __restrict__ ln_g, const float* __restrict__ ln_b,
    float* __restrict__ out) {
  __shared__ float rowbuf[16][260];
  int mt = blockIdx.x;
  int tid = threadIdx.x, wid = tid >> 6, lane = tid & 63;
  int lr = lane & 15, lk = lane >> 4;
  int m0 = mt * 16;
  f32x4 acc[4] = {};
  for (int k0 = 0; k0 < 256; k0 += 32) {
    short8 af = *(const short8*)(Ob + (size_t)(m0 + lr) * 256 + k0 + lk * 8);
#pragma unroll
    for (int j = 0; j < 4; j++) {
      short8 bfr = load_f32x8_bf16(out_w + (size_t)(wid * 64 + j * 16 + lr) * 256 + k0 + lk * 8);
      acc[j] = __builtin_amdgcn_mfma_f32_16x16x32_bf16(af, bfr, acc[j], 0, 0, 0);
    }
  }
#pragma unroll
  for (int j = 0; j < 4; j++) {
    int n = wid * 64 + j * 16 + lr;
    float bv = out_b[n];
#pragma unroll
    for (int r = 0; r < 4; r++) {
      int m = m0 + lk * 4 + r;
      rowbuf[lk * 4 + r][n] = acc[j][r] + bv + queries[(size_t)m * 256 + n];
    }
  }
  __syncthreads();
  int row = tid >> 4, seg = tid & 15;
  float s1 = 0.f, s2 = 0.f, vals[16];
#pragma unroll
  for (int c = 0; c < 16; c++) {
    float v = rowbuf[row][seg * 16 + c];
    vals[c] = v; s1 += v; s2 += v * v;
  }
#pragma unroll
  for (int d = 1; d < 16; d <<= 1) {
    s1 += __shfl_xor(s1, d, 64);
    s2 += __shfl_xor(s2, d, 64);
  }
  float mean = s1 * (1.f / 256.f);
  float var = s2 * (1.f / 256.f) - mean * mean;
  float rstd = rsqrtf(var + 1e-5f);
  int m = m0 + row;
#pragma unroll
  for (int c = 0; c < 16; c++) {
    int col = seg * 16 + c;
    out[(size_t)m * 256 + col] = (vals[c] - mean) * rstd * ln_g[col] + ln_b[col];
  }
}

extern "C" void kernel_launch(void* const* d_in, const int* in_sizes, int n_in,
                              void* d_out, int out_size, void* d_ws, size_t ws_size,
                              hipStream_t stream) {
  const float* sources  = (const float*)d_in[0];
  const float* queries  = (const float*)d_in[1];
  const int* attn_mask  = (const int*)d_in[2];
  const float* in_proj_w = (const float*)d_in[3];
  const float* in_proj_b = (const float*)d_in[4];
  const float* out_w = (const float*)d_in[5];
  const float* out_b = (const float*)d_in[6];
  const float* ln_g  = (const float*)d_in[7];
  const float* ln_b  = (const float*)d_in[8];
  float* out = (float*)d_out;

  // workspace layout (shorts): mask64 | Qb | Kb | Vt | Ob | Wb
  unsigned short* base = (unsigned short*)d_ws;
  unsigned long long* mask64 = (unsigned long long*)d_ws;          // 262144 u64 = 1,048,576 shorts
  unsigned short* Qb = base + 1048576;                             // [B,H,Q,32]  2,097,152
  unsigned short* Kb = Qb + 2097152;                               // [B,H,P,32]  8,388,608
  unsigned short* Vt = Kb + 8388608;                               // [B,H,32,P]  8,388,608
  unsigned short* Ob = Vt + 8388608;                               // [B,Q,256]   2,097,152
  unsigned short* Wb = Ob + 2097152;                               // 768x256 bf16 = 196,608

  dim3 b256(256), b512(512);
  pack_w_kernel<<<96, b256, 0, stream>>>(in_proj_w, Wb);
  pack_mask_kernel<<<2048, b256, 0, stream>>>(attn_mask, mask64);
  proj_kernel<4><<<128, b512, 0, stream>>>(queries, Wb, in_proj_b, Qb, nullptr, 0);
  proj_kernel<8><<<512, b512, 0, stream>>>(sources, Wb + 256 * 256, in_proj_b + 256, Kb, Vt, 1);
  attn_kernel<<<dim3(8, 128), b256, 0, stream>>>(Qb, Kb, Vt, mask64, Ob);
  outln_kernel<<<512, b256, 0, stream>>>(Ob, out_w, out_b, queries, ln_g, ln_b, out);
}